// Round 1
// baseline (133.128 us; speedup 1.0000x reference)
//
#include <hip/hip_runtime.h>
#include <hip/hip_bf16.h>

// Problem constants
#define DD 512
#define HIDN 64
#define NTREE 64
#define NIN 7           // internal nodes
#define PPTC 3607       // NI*D + NI + NL*2
#define TOTP 230912     // PPT*T + T
#define SWROWS 448      // T*NI

typedef __attribute__((ext_vector_type(8))) short bf16x8;
typedef __attribute__((ext_vector_type(4))) float f32x4;

__device__ __forceinline__ unsigned short f2bf(float f) {
  unsigned u = __float_as_uint(f);
  unsigned r = (u + 0x7FFFu + ((u >> 16) & 1u)) >> 16;   // RNE
  return (unsigned short)r;
}
__device__ __forceinline__ float bf2f(unsigned short h) {
  return __uint_as_float(((unsigned)h) << 16);
}
__device__ __forceinline__ float sigmoidf_(float x) {
  return 1.0f / (1.0f + __expf(-x));
}

// ---------------------------------------------------------------------------
// Kernel 1: train path. Block = 256 thr (4 waves), 64 rows/block, 128 blocks.
// GEMM1 (512->64, bf16 MFMA) + LN + relu -> GEMM2 (64->64, bf16 MFMA) + relu
// -> column sums accumulated to c_accum (mean done later).
// ---------------------------------------------------------------------------
__global__ __launch_bounds__(256) void k_train(
    const float* __restrict__ Xtr, const float* __restrict__ W1,
    const float* __restrict__ b1, const float* __restrict__ g1,
    const float* __restrict__ be1, const float* __restrict__ W2,
    const float* __restrict__ b2, float* __restrict__ c_accum)
{
  __shared__ __align__(16) char smem[49408];
  char* Xc  = smem;            // [64][128] bf16 = 16384 (K-chunk of X)
  char* W1c = smem + 16384;    // [64][128] bf16 = 16384 (K-chunk of W1)
  char* Hl  = smem + 32768;    // 4 waves * [16][64] bf16 (2048 each)
  char* W2l = smem + 40960;    // [64][64] bf16 = 8192
  float* cpart = (float*)(smem + 49152); // 64 floats

  const int tid = threadIdx.x;
  const int lane = tid & 63;
  const int wv = tid >> 6;
  const int l15 = lane & 15;
  const int gq = lane >> 4;
  const int rb0 = blockIdx.x * 64;

  // stage W2 as bf16 (B-operand layout [n][k], swizzled), zero cpart
#pragma unroll
  for (int s = 0; s < 4; ++s) {
    int fidx = tid + s * 256;            // 1024 float4s
    int n = fidx >> 4, kq = fidx & 15;
    float4 v = ((const float4*)W2)[n * 16 + kq];
    uint2 pk;
    pk.x = (unsigned)f2bf(v.x) | ((unsigned)f2bf(v.y) << 16);
    pk.y = (unsigned)f2bf(v.z) | ((unsigned)f2bf(v.w) << 16);
    int off = n * 128 + kq * 8; off ^= (n & 7) << 4;
    *(uint2*)(W2l + off) = pk;
  }
  if (tid < 64) cpart[tid] = 0.0f;

  f32x4 acc1[4];
#pragma unroll
  for (int nt = 0; nt < 4; ++nt) { f32x4 z = {0.f,0.f,0.f,0.f}; acc1[nt] = z; }

  for (int kc = 0; kc < 4; ++kc) {
    __syncthreads();
    // stage X[64][128] and W1[64][128] chunks (fp32 -> bf16)
#pragma unroll
    for (int s = 0; s < 8; ++s) {
      int idx = tid + s * 256;           // 2048 slots
      int m = idx >> 5, kq = idx & 31;
      float4 v = ((const float4*)Xtr)[(rb0 + m) * 128 + kc * 32 + kq];
      uint2 pk;
      pk.x = (unsigned)f2bf(v.x) | ((unsigned)f2bf(v.y) << 16);
      pk.y = (unsigned)f2bf(v.z) | ((unsigned)f2bf(v.w) << 16);
      int off = m * 256 + kq * 8; off ^= (m & 7) << 4;
      *(uint2*)(Xc + off) = pk;
      float4 w = ((const float4*)W1)[m * 128 + kc * 32 + kq];
      uint2 pw;
      pw.x = (unsigned)f2bf(w.x) | ((unsigned)f2bf(w.y) << 16);
      pw.y = (unsigned)f2bf(w.z) | ((unsigned)f2bf(w.w) << 16);
      *(uint2*)(W1c + off) = pw;
    }
    __syncthreads();
#pragma unroll
    for (int ks = 0; ks < 4; ++ks) {
      int mrow = wv * 16 + l15;
      int aoff = mrow * 256 + ks * 64 + gq * 16; aoff ^= (mrow & 7) << 4;
      bf16x8 afr = *(const bf16x8*)(Xc + aoff);
#pragma unroll
      for (int nt = 0; nt < 4; ++nt) {
        int n = nt * 16 + l15;
        int boff = n * 256 + ks * 64 + gq * 16; boff ^= (n & 7) << 4;
        bf16x8 bfr = *(const bf16x8*)(W1c + boff);
        acc1[nt] = __builtin_amdgcn_mfma_f32_16x16x32_bf16(afr, bfr, acc1[nt], 0, 0, 0);
      }
    }
  }

  // y = acc1 + b1 ; LN over 64 cols per row ; relu ; h -> LDS (bf16, swizzled)
  float b1v[4], g1v[4], be1v[4], b2v[4];
#pragma unroll
  for (int nt = 0; nt < 4; ++nt) {
    int c = nt * 16 + l15;
    b1v[nt] = b1[c]; g1v[nt] = g1[c]; be1v[nt] = be1[c]; b2v[nt] = b2[c];
  }
  float yv[4][4], s_[4], q_[4];
#pragma unroll
  for (int i = 0; i < 4; ++i) {
    float s = 0.f, q = 0.f;
#pragma unroll
    for (int nt = 0; nt < 4; ++nt) {
      float y = acc1[nt][i] + b1v[nt];
      yv[nt][i] = y; s += y; q += y * y;
    }
    s_[i] = s; q_[i] = q;
  }
#pragma unroll
  for (int off = 1; off < 16; off <<= 1) {
#pragma unroll
    for (int i = 0; i < 4; ++i) {
      s_[i] += __shfl_xor(s_[i], off);
      q_[i] += __shfl_xor(q_[i], off);
    }
  }
  char* Hw = Hl + wv * 2048;
#pragma unroll
  for (int i = 0; i < 4; ++i) {
    float m = s_[i] * (1.0f / 64.0f);
    float var = q_[i] * (1.0f / 64.0f) - m * m;
    float rstd = rsqrtf(var + 1e-5f);
    int mrow = gq * 4 + i;
#pragma unroll
    for (int nt = 0; nt < 4; ++nt) {
      float h = (yv[nt][i] - m) * rstd * g1v[nt] + be1v[nt];
      h = fmaxf(h, 0.0f);
      int col = nt * 16 + l15;
      int off2 = mrow * 128 + col * 2; off2 ^= (mrow & 7) << 4;
      *(unsigned short*)(Hw + off2) = f2bf(h);
    }
  }
  __syncthreads();   // Hl visibility (cheap, once per block)

  // GEMM2: z = h @ W2^T (16x64 per wave)
  f32x4 acc2[4];
#pragma unroll
  for (int nt = 0; nt < 4; ++nt) { f32x4 z = {0.f,0.f,0.f,0.f}; acc2[nt] = z; }
#pragma unroll
  for (int ks = 0; ks < 2; ++ks) {
    int aoff = l15 * 128 + ks * 64 + gq * 16; aoff ^= (l15 & 7) << 4;
    bf16x8 afr = *(const bf16x8*)(Hw + aoff);
#pragma unroll
    for (int nt = 0; nt < 4; ++nt) {
      int n = nt * 16 + l15;
      int boff = n * 128 + ks * 64 + gq * 16; boff ^= (n & 7) << 4;
      bf16x8 bfr = *(const bf16x8*)(W2l + boff);
      acc2[nt] = __builtin_amdgcn_mfma_f32_16x16x32_bf16(afr, bfr, acc2[nt], 0, 0, 0);
    }
  }
  // relu(z+b2), sum over 16 rows of the strip, accumulate
  float cs[4];
#pragma unroll
  for (int nt = 0; nt < 4; ++nt) {
    float s = 0.f;
#pragma unroll
    for (int i = 0; i < 4; ++i) {
      float z = acc2[nt][i] + b2v[nt];
      s += fmaxf(z, 0.0f);
    }
    cs[nt] = s;
  }
#pragma unroll
  for (int nt = 0; nt < 4; ++nt) {
    cs[nt] += __shfl_xor(cs[nt], 16);
    cs[nt] += __shfl_xor(cs[nt], 32);
  }
  if (lane < 16) {
#pragma unroll
    for (int nt = 0; nt < 4; ++nt) atomicAdd(&cpart[nt * 16 + l15], cs[nt]);
  }
  __syncthreads();
  if (tid < 64) atomicAdd(&c_accum[tid], cpart[tid]);
}

// ---------------------------------------------------------------------------
// Kernel 2: head MLP (fp32, tiny). 1 block x 128 threads.
// ---------------------------------------------------------------------------
__global__ __launch_bounds__(128) void k_head(
    const float* __restrict__ c_accum,
    const float* __restrict__ H1, const float* __restrict__ hb1,
    const float* __restrict__ g2, const float* __restrict__ be2,
    const float* __restrict__ H2, const float* __restrict__ hb2,
    float* __restrict__ u2out)
{
  __shared__ float clds[64];
  __shared__ float u1lds[128];
  __shared__ float red[4];
  int tid = threadIdx.x;
  if (tid < 64) clds[tid] = c_accum[tid] * (1.0f / 8192.0f);
  __syncthreads();
  float acc = hb1[tid];
  for (int k = 0; k < 64; ++k) acc += clds[k] * H1[tid * 64 + k];
  float s = acc, q = acc * acc;
#pragma unroll
  for (int off = 1; off < 64; off <<= 1) { s += __shfl_xor(s, off); q += __shfl_xor(q, off); }
  int wv = tid >> 6;
  if ((tid & 63) == 0) { red[wv * 2] = s; red[wv * 2 + 1] = q; }
  __syncthreads();
  float S = red[0] + red[2], Q = red[1] + red[3];
  float m = S * (1.0f / 128.0f);
  float var = Q * (1.0f / 128.0f) - m * m;
  float rstd = rsqrtf(var + 1e-5f);
  float u1 = fmaxf((acc - m) * rstd * g2[tid] + be2[tid], 0.0f);
  u1lds[tid] = u1;
  __syncthreads();
  float a2 = hb2[tid];
  for (int k = 0; k < 128; ++k) a2 += u1lds[k] * H2[tid * 128 + k];
  u2out[tid] = fmaxf(a2, 0.0f);
}

// ---------------------------------------------------------------------------
// Kernel 3: params = u2 @ H3^T + hb3, routed to sw(bf16)/sb/ll/tw.
// 4 lanes per row, 64 rows/block, 3608 blocks. Streams 118 MB of H3.
// ---------------------------------------------------------------------------
__global__ __launch_bounds__(256) void k_params(
    const float* __restrict__ H3, const float* __restrict__ hb3,
    const float* __restrict__ u2,
    unsigned short* __restrict__ Bsw, float* __restrict__ sb,
    float* __restrict__ ll, float* __restrict__ tw)
{
  __shared__ float u2l[128];
  int tid = threadIdx.x;
  if (tid < 128) u2l[tid] = u2[tid];
  __syncthreads();
  int row = blockIdx.x * 64 + (tid >> 2);
  int sub = tid & 3;
  float acc = 0.0f;
  const float4* H4 = (const float4*)H3;
#pragma unroll
  for (int j = 0; j < 8; ++j) {
    int f = j * 4 + sub;
    float4 v = H4[row * 32 + f];
    acc += v.x * u2l[f * 4] + v.y * u2l[f * 4 + 1] + v.z * u2l[f * 4 + 2] + v.w * u2l[f * 4 + 3];
  }
  acc += __shfl_xor(acc, 1);
  acc += __shfl_xor(acc, 2);
  if (sub == 0) {
    float val = acc + hb3[row];
    if (row >= 230848) {
      tw[row - 230848] = val;
    } else {
      int t = row / PPTC;
      int r = row - t * PPTC;
      if (r < 3584) {
        int n = r >> 9, d = r & 511;
        Bsw[(t * 7 + n) * 512 + d] = f2bf(val);
      } else if (r < 3591) {
        sb[t * 7 + (r - 3584)] = val;
      } else {
        ll[t * 16 + (r - 3591)] = val;
      }
    }
  }
}

// ---------------------------------------------------------------------------
// Kernel 4: q[t][l][c] = 2 * softmax(tw)[t] * softmax(ll[t,l,:])[c]
// ---------------------------------------------------------------------------
__global__ __launch_bounds__(64) void k_qprep(
    const float* __restrict__ ll, const float* __restrict__ tw,
    float* __restrict__ q)
{
  int t = threadIdx.x;
  float x = tw[t];
  float m = x;
#pragma unroll
  for (int off = 1; off < 64; off <<= 1) m = fmaxf(m, __shfl_xor(m, off));
  float e = __expf(x - m);
  float s = e;
#pragma unroll
  for (int off = 1; off < 64; off <<= 1) s += __shfl_xor(s, off);
  float w = e / s;
#pragma unroll
  for (int l = 0; l < 8; ++l) {
    float a = ll[t * 16 + l * 2], b = ll[t * 16 + l * 2 + 1];
    float mm = fmaxf(a, b);
    float e0 = __expf(a - mm), e1 = __expf(b - mm);
    float inv = 2.0f * w / (e0 + e1);
    q[t * 16 + l * 2] = e0 * inv;
    q[t * 16 + l * 2 + 1] = e1 * inv;
  }
}

// ---------------------------------------------------------------------------
// Kernel 5: main inference. Block = 256 thr (4 waves), 32 rows x 448 cols.
// bf16 MFMA GEMM (K=512, BK=32) fused with sigmoid + soft tree + mixing.
// ---------------------------------------------------------------------------
__global__ __launch_bounds__(256) void k_test(
    const float* __restrict__ Xt, const unsigned short* __restrict__ Bsw,
    const float* __restrict__ sb, const float* __restrict__ q,
    float* __restrict__ out)
{
  __shared__ __align__(16) char smem[36864];
  char* Xl = smem;                       // [32][32] bf16 = 2048
  char* Bl = smem + 2048;                // [448][32] bf16 = 28672
  char* Pl = smem;                       // p tile [32][456] bf16 (alias, 29184)
  float* ql  = (float*)(smem + 30720);   // 1024 floats
  float* sbl = (float*)(smem + 34816);   // 448 floats
  float* outl = (float*)(smem + 36608);  // 64 floats

  int tid = threadIdx.x;
  int lane = tid & 63;
  int wv = tid >> 6;
  int l15 = lane & 15;
  int gq = lane >> 4;
  int bm0 = blockIdx.x * 32;

  for (int s = tid; s < 1024; s += 256) ql[s] = q[s];
  for (int s = tid; s < 448; s += 256) sbl[s] = sb[s];
  if (tid < 64) outl[tid] = 0.0f;

  f32x4 acc[2][7];
#pragma unroll
  for (int mt = 0; mt < 2; ++mt)
#pragma unroll
    for (int nt = 0; nt < 7; ++nt) { f32x4 z = {0.f,0.f,0.f,0.f}; acc[mt][nt] = z; }

  int xm = tid >> 3, xk = tid & 7;
  for (int kt = 0; kt < 16; ++kt) {
    __syncthreads();
    // X stage: 32x32 fp32 -> bf16
    {
      float4 v = ((const float4*)Xt)[(bm0 + xm) * 128 + kt * 8 + xk];
      uint2 pk;
      pk.x = (unsigned)f2bf(v.x) | ((unsigned)f2bf(v.y) << 16);
      pk.y = (unsigned)f2bf(v.z) | ((unsigned)f2bf(v.w) << 16);
      int off = xm * 64 + xk * 8; off ^= (xm & 7) << 4;
      *(uint2*)(Xl + off) = pk;
    }
    // B stage: 448x32 bf16 (already bf16 in ws)
#pragma unroll
    for (int s2 = 0; s2 < 7; ++s2) {
      int idx = tid + s2 * 256;
      int n = idx >> 2, part = idx & 3;
      uint4 bv = ((const uint4*)Bsw)[n * 64 + kt * 4 + part];
      int off = n * 64 + part * 16; off ^= (n & 7) << 4;
      *(uint4*)(Bl + off) = bv;
    }
    __syncthreads();
    bf16x8 afr[2];
#pragma unroll
    for (int mt = 0; mt < 2; ++mt) {
      int m = mt * 16 + l15;
      int off = m * 64 + gq * 16; off ^= (m & 7) << 4;
      afr[mt] = *(const bf16x8*)(Xl + off);
    }
#pragma unroll
    for (int nt = 0; nt < 7; ++nt) {
      int n = wv * 112 + nt * 16 + l15;
      int off = n * 64 + gq * 16; off ^= (n & 7) << 4;
      bf16x8 bfr = *(const bf16x8*)(Bl + off);
      acc[0][nt] = __builtin_amdgcn_mfma_f32_16x16x32_bf16(afr[0], bfr, acc[0][nt], 0, 0, 0);
      acc[1][nt] = __builtin_amdgcn_mfma_f32_16x16x32_bf16(afr[1], bfr, acc[1][nt], 0, 0, 0);
    }
  }
  __syncthreads();   // all frag reads done; Pl aliases staging region

  // p = sigmoid(logit + sb), bf16 into Pl (row stride 456 elems to dodge conflicts)
#pragma unroll
  for (int mt = 0; mt < 2; ++mt)
#pragma unroll
    for (int nt = 0; nt < 7; ++nt) {
      int col = wv * 112 + nt * 16 + l15;
      float sbv = sbl[col];
#pragma unroll
      for (int i = 0; i < 4; ++i) {
        int row = mt * 16 + gq * 4 + i;
        float p = sigmoidf_(acc[mt][nt][i] + sbv);
        *(unsigned short*)(Pl + row * 912 + col * 2) = f2bf(p);
      }
    }
  __syncthreads();

  // soft tree: 32 rows x 64 trees = 2048 tasks, 8 per thread
#pragma unroll
  for (int it = 0; it < 8; ++it) {
    int id = tid + it * 256;
    int row = id & 31;
    int t = id >> 5;
    const unsigned short* pr = (const unsigned short*)(Pl + row * 912) + t * 7;
    float p0 = bf2f(pr[0]), p1 = bf2f(pr[1]), p2 = bf2f(pr[2]);
    float p3 = bf2f(pr[3]), p4 = bf2f(pr[4]), p5 = bf2f(pr[5]), p6 = bf2f(pr[6]);
    float n0 = 1.f - p0, n1 = 1.f - p1, n2 = 1.f - p2;
    float a00 = n0 * n1, a01 = n0 * p1, a10 = p0 * n2, a11 = p0 * p2;
    float L0 = a00 * (1.f - p3), L1 = a00 * p3;
    float L2 = a01 * (1.f - p4), L3 = a01 * p4;
    float L4 = a10 * (1.f - p5), L5 = a10 * p5;
    float L6 = a11 * (1.f - p6), L7 = a11 * p6;
    const float* qt = ql + t * 16;
    float o0 = L0*qt[0] + L1*qt[2] + L2*qt[4] + L3*qt[6] + L4*qt[8] + L5*qt[10] + L6*qt[12] + L7*qt[14];
    float o1 = L0*qt[1] + L1*qt[3] + L2*qt[5] + L3*qt[7] + L4*qt[9] + L5*qt[11] + L6*qt[13] + L7*qt[15];
    atomicAdd(&outl[row * 2], o0);
    atomicAdd(&outl[row * 2 + 1], o1);
  }
  __syncthreads();
  if (tid < 64) out[bm0 * 2 + tid] = outl[tid];
}

// ---------------------------------------------------------------------------
extern "C" void kernel_launch(void* const* d_in, const int* in_sizes, int n_in,
                              void* d_out, int out_size, void* d_ws, size_t ws_size,
                              hipStream_t stream)
{
  const float* Xtr = (const float*)d_in[0];
  const float* Xte = (const float*)d_in[1];
  // d_in[2] = y_train (unused by reference)
  const float* W1  = (const float*)d_in[3];
  const float* b1  = (const float*)d_in[4];
  const float* g1  = (const float*)d_in[5];
  const float* be1 = (const float*)d_in[6];
  const float* W2  = (const float*)d_in[7];
  const float* b2  = (const float*)d_in[8];
  const float* H1  = (const float*)d_in[9];
  const float* hb1 = (const float*)d_in[10];
  const float* g2  = (const float*)d_in[11];
  const float* be2 = (const float*)d_in[12];
  const float* H2  = (const float*)d_in[13];
  const float* hb2 = (const float*)d_in[14];
  const float* H3  = (const float*)d_in[15];
  const float* hb3 = (const float*)d_in[16];
  float* out = (float*)d_out;
  char* ws = (char*)d_ws;

  float* c_accum = (float*)ws;                 // 64 f32
  float* u2      = (float*)(ws + 256);         // 128 f32
  float* sb      = (float*)(ws + 768);         // 448 f32
  float* ll      = (float*)(ws + 2560);        // 1024 f32
  float* tw      = (float*)(ws + 6656);        // 64 f32
  float* q       = (float*)(ws + 6912);        // 1024 f32
  unsigned short* Bsw = (unsigned short*)(ws + 11008); // 448*512 bf16

  hipMemsetAsync(c_accum, 0, 64 * sizeof(float), stream);
  k_train<<<128, 256, 0, stream>>>(Xtr, W1, b1, g1, be1, W2, b2, c_accum);
  k_head<<<1, 128, 0, stream>>>(c_accum, H1, hb1, g2, be2, H2, hb2, u2);
  k_params<<<3608, 256, 0, stream>>>(H3, hb3, u2, Bsw, sb, ll, tw);
  k_qprep<<<1, 64, 0, stream>>>(ll, tw, q);
  k_test<<<1024, 256, 0, stream>>>(Xte, Bsw, sb, q, out);
}